// Round 1
// baseline (29.827 us; speedup 1.0000x reference)
//
#include <hip/hip_runtime.h>
#include <math.h>

// Problem constants (match reference)
constexpr int   BATCH = 32;
constexpr int   S     = 262144;
constexpr int   BLK   = 128;          // samples per filter block
constexpr int   NB    = S / BLK;      // 2048 blocks per batch row
constexpr float SRATE = 44100.0f;
constexpr float FC_MIN = 2000.0f, FC_MAX = 20000.0f;
constexpr float Q_MIN  = 0.1f,    Q_MAX  = 10.0f;

// One thread per (batch, block): compute control means -> biquad coeffs ->
// run 128-sample direct-form-II-transposed recurrence from zero state.
__global__ __launch_bounds__(256) void lowpass_kernel(
    const float* __restrict__ x,
    const float* __restrict__ cp,
    float* __restrict__ out,
    float* __restrict__ fc_out,
    float* __restrict__ q_out)
{
    const int tid = blockIdx.x * blockDim.x + threadIdx.x;  // 0 .. 65535
    const int b   = tid >> 11;          // / NB
    const int blk = tid & (NB - 1);     // % NB

    // ---- control-parameter means (two channels, 128 samples each) ----
    const float4* c0 = reinterpret_cast<const float4*>(
        cp + (size_t)b * 2 * S + (size_t)blk * BLK);
    const float4* c1 = c0 + S / 4;      // channel 1 offset (S floats)

    float s0 = 0.0f, s1 = 0.0f;
#pragma unroll 8
    for (int j = 0; j < BLK / 4; ++j) {
        float4 v = c0[j];
        s0 += (v.x + v.y) + (v.z + v.w);
    }
#pragma unroll 8
    for (int j = 0; j < BLK / 4; ++j) {
        float4 v = c1[j];
        s1 += (v.x + v.y) + (v.z + v.w);
    }
    const float m0 = s0 * (1.0f / BLK);
    const float m1 = s1 * (1.0f / BLK);

    const float fc = m0 * (FC_MAX - FC_MIN) + FC_MIN;
    const float q  = m1 * (Q_MAX - Q_MIN) + Q_MIN;

    // ---- RBJ low-pass biquad coefficients, normalized by a0 ----
    const float w0 = 6.283185307179586f * fc / SRATE;
    float sw, cw;
    sincosf(w0, &sw, &cw);
    const float alpha = sw / (2.0f * q);
    const float a0inv = 1.0f / (1.0f + alpha);
    const float b0c = (1.0f - cw) * 0.5f * a0inv;   // b2 == b0
    const float b1c = (1.0f - cw) * a0inv;
    const float a1c = (-2.0f * cw) * a0inv;
    const float a2c = (1.0f - alpha) * a0inv;

    // ---- 128-sample biquad (DF2T), zero initial state ----
    const float4* xp = reinterpret_cast<const float4*>(
        x + (size_t)b * S + (size_t)blk * BLK);
    float4* op = reinterpret_cast<float4*>(
        out + (size_t)b * S + (size_t)blk * BLK);

    float z1 = 0.0f, z2 = 0.0f;
#pragma unroll 8
    for (int j = 0; j < BLK / 4; ++j) {
        float4 xv = xp[j];
        float4 yv;

        {   float xn = xv.x;
            float y  = b0c * xn + z1;
            float z1n = b1c * xn - a1c * y + z2;
            z2 = b0c * xn - a2c * y;
            z1 = z1n;
            yv.x = y; }
        {   float xn = xv.y;
            float y  = b0c * xn + z1;
            float z1n = b1c * xn - a1c * y + z2;
            z2 = b0c * xn - a2c * y;
            z1 = z1n;
            yv.y = y; }
        {   float xn = xv.z;
            float y  = b0c * xn + z1;
            float z1n = b1c * xn - a1c * y + z2;
            z2 = b0c * xn - a2c * y;
            z1 = z1n;
            yv.z = y; }
        {   float xn = xv.w;
            float y  = b0c * xn + z1;
            float z1n = b1c * xn - a1c * y + z2;
            z2 = b0c * xn - a2c * y;
            z1 = z1n;
            yv.w = y; }

        op[j] = yv;
    }

    // ---- per-block fc / q outputs (row-major (B, NB) == tid order) ----
    fc_out[tid] = fc;
    q_out[tid]  = q;
}

extern "C" void kernel_launch(void* const* d_in, const int* in_sizes, int n_in,
                              void* d_out, int out_size, void* d_ws, size_t ws_size,
                              hipStream_t stream) {
    const float* x  = (const float*)d_in[0];   // (32, 1, 262144)
    const float* cp = (const float*)d_in[1];   // (32, 2, 262144)

    float* out    = (float*)d_out;                      // 32*262144
    float* fc_out = out + (size_t)BATCH * S;            // 32*2048
    float* q_out  = fc_out + (size_t)BATCH * NB;        // 32*2048

    const int total = BATCH * NB;   // 65536 threads, one per audio block
    lowpass_kernel<<<total / 256, 256, 0, stream>>>(x, cp, out, fc_out, q_out);
}

// Round 2
// 27.719 us; speedup vs baseline: 1.0760x; 1.0760x over previous
//
#include <hip/hip_runtime.h>
#include <math.h>

// Problem constants (match reference)
constexpr int   BATCH = 32;
constexpr int   S     = 262144;
constexpr int   BLK   = 128;          // samples per filter block
constexpr int   NB    = S / BLK;      // 2048 blocks per batch row
constexpr float SRATE = 44100.0f;
constexpr float FC_MIN = 2000.0f, FC_MAX = 20000.0f;
constexpr float Q_MIN  = 0.1f,    Q_MAX  = 10.0f;

constexpr int WPB     = 64;           // audio blocks per workgroup
constexpr int THREADS = 256;

// LDS holds the workgroup's 64 blocks of x (32 KB), float4-slot swizzled:
// xs4[B*32 + j'] contains sample-float4 (j' ^ (B&7)) of block B.
// Recurrence read (lane t = block): xs4[t*32 + (j ^ (t&7))] -> 8 bank-groups
// instead of the 64-way conflict of an unswizzled row-major layout, while the
// LDS destination of global_load_lds stays linear (lane-contiguous).

__global__ __launch_bounds__(THREADS) void lowpass_kernel(
    const float* __restrict__ x,
    const float* __restrict__ cp,
    float* __restrict__ out,
    float* __restrict__ fc_out,
    float* __restrict__ q_out)
{
    __shared__ float xs[WPB * BLK];        // 32 KB
    __shared__ float ms0[WPB], ms1[WPB];   // per-block control sums

    const int t    = threadIdx.x;
    const int wg   = blockIdx.x;           // 0..1023
    const int b    = wg >> 5;              // batch row (32 wg per row)
    const int blk0 = (wg & 31) * WPB;      // first audio block of this wg

    const size_t xbase = (size_t)b * S + (size_t)blk0 * BLK;   // float index
    const float4* x4 = reinterpret_cast<const float4*>(x + xbase);

    // ---- phase 0: DMA x -> LDS, source-swizzled, dest linear --------------
#pragma unroll
    for (int k = 0; k < 8; ++k) {
        const int D  = k * THREADS + t;      // linear float4 slot in LDS
        const int B  = D >> 5;               // block row
        const int jp = D & 31;               // slot within row
        const int src4 = B * 32 + (jp ^ (B & 7));
        // wave-uniform LDS base; HW adds lane*16
        float* ldsb = xs + (size_t)(k * THREADS + (t & ~63)) * 4;
        __builtin_amdgcn_global_load_lds(
            (const __attribute__((address_space(1))) void*)(x4 + src4),
            (__attribute__((address_space(3))) void*)ldsb,
            16, 0, 0);
    }

    // ---- phase 1: control-param means (coalesced + shfl reduce) -----------
    const size_t cpb = (size_t)b * 2 * S + (size_t)blk0 * BLK;
    const float4* c0 = reinterpret_cast<const float4*>(cp + cpb);
    const float4* c1 = reinterpret_cast<const float4*>(cp + cpb + S);

    float4 v0[8], v1[8];
#pragma unroll
    for (int k = 0; k < 8; ++k) {
        const int f = k * THREADS + t;
        v0[k] = c0[f];
        v1[k] = c1[f];
    }
#pragma unroll
    for (int k = 0; k < 8; ++k) {
        float s0 = (v0[k].x + v0[k].y) + (v0[k].z + v0[k].w);
        float s1 = (v1[k].x + v1[k].y) + (v1[k].z + v1[k].w);
#pragma unroll
        for (int m = 1; m < 32; m <<= 1) {
            s0 += __shfl_xor(s0, m);
            s1 += __shfl_xor(s1, m);
        }
        if ((t & 31) == 0) {                 // one writer per 32-lane segment
            const int B = k * 8 + (t >> 5);
            ms0[B] = s0;
            ms1[B] = s1;
        }
    }

    __syncthreads();   // drains the x DMA (vmcnt 0) + means visible

    // ---- phase 2+3: coeffs + 128-sample DF2T recurrence (wave 0 only) -----
    if (t < WPB) {
        const float m0 = ms0[t] * (1.0f / BLK);
        const float m1 = ms1[t] * (1.0f / BLK);
        const float fc = m0 * (FC_MAX - FC_MIN) + FC_MIN;
        const float q  = m1 * (Q_MAX - Q_MIN) + Q_MIN;

        const int gblk = b * NB + blk0 + t;
        fc_out[gblk] = fc;
        q_out[gblk]  = q;

        const float w0 = 6.283185307179586f * fc / SRATE;
        float sw, cw;
        sincosf(w0, &sw, &cw);
        const float alpha = sw / (2.0f * q);
        const float a0inv = 1.0f / (1.0f + alpha);
        const float b0c = (1.0f - cw) * 0.5f * a0inv;   // b2 == b0
        const float b1c = (1.0f - cw) * a0inv;
        const float a1c = (-2.0f * cw) * a0inv;
        const float a2c = (1.0f - alpha) * a0inv;

        float4* xs4 = reinterpret_cast<float4*>(xs);
        const int swz = t & 7;
        float z1 = 0.0f, z2 = 0.0f;
#pragma unroll 8
        for (int j = 0; j < 32; ++j) {
            const int a = t * 32 + (j ^ swz);
            float4 xv = xs4[a];
            float4 yv;
            {   float xn = xv.x;
                float y   = b0c * xn + z1;
                float z1n = b1c * xn - a1c * y + z2;
                z2 = b0c * xn - a2c * y;  z1 = z1n;  yv.x = y; }
            {   float xn = xv.y;
                float y   = b0c * xn + z1;
                float z1n = b1c * xn - a1c * y + z2;
                z2 = b0c * xn - a2c * y;  z1 = z1n;  yv.y = y; }
            {   float xn = xv.z;
                float y   = b0c * xn + z1;
                float z1n = b1c * xn - a1c * y + z2;
                z2 = b0c * xn - a2c * y;  z1 = z1n;  yv.z = y; }
            {   float xn = xv.w;
                float y   = b0c * xn + z1;
                float z1n = b1c * xn - a1c * y + z2;
                z2 = b0c * xn - a2c * y;  z1 = z1n;  yv.w = y; }
            xs4[a] = yv;   // in-place: each thread owns its row
        }
    }

    __syncthreads();

    // ---- phase 4: cooperative coalesced store (inverse swizzle on global) -
    float4* o4 = reinterpret_cast<float4*>(out + xbase);
    const float4* xs4 = reinterpret_cast<const float4*>(xs);
#pragma unroll
    for (int k = 0; k < 8; ++k) {
        const int D  = k * THREADS + t;
        const int B  = D >> 5;
        const int jp = D & 31;
        o4[B * 32 + (jp ^ (B & 7))] = xs4[D];
    }
}

extern "C" void kernel_launch(void* const* d_in, const int* in_sizes, int n_in,
                              void* d_out, int out_size, void* d_ws, size_t ws_size,
                              hipStream_t stream) {
    const float* x  = (const float*)d_in[0];   // (32, 1, 262144)
    const float* cp = (const float*)d_in[1];   // (32, 2, 262144)

    float* out    = (float*)d_out;                      // 32*262144
    float* fc_out = out + (size_t)BATCH * S;            // 32*2048
    float* q_out  = fc_out + (size_t)BATCH * NB;        // 32*2048

    const int total_blocks = BATCH * NB;                // 65536 audio blocks
    const int grid = total_blocks / WPB;                // 1024 workgroups
    lowpass_kernel<<<grid, THREADS, 0, stream>>>(x, cp, out, fc_out, q_out);
}

// Round 3
// 27.438 us; speedup vs baseline: 1.0871x; 1.0103x over previous
//
#include <hip/hip_runtime.h>
#include <math.h>

// Problem constants (match reference)
constexpr int   BATCH = 32;
constexpr int   S     = 262144;
constexpr int   BLK   = 128;          // samples per filter block
constexpr int   NB    = S / BLK;      // 2048 blocks per batch row
constexpr float SRATE = 44100.0f;
constexpr float FC_MIN = 2000.0f, FC_MAX = 20000.0f;
constexpr float Q_MIN  = 0.1f,    Q_MAX  = 10.0f;

constexpr int WPB     = 32;           // audio blocks per workgroup (halved: occupancy)
constexpr int THREADS = 256;
constexpr int X4      = WPB * BLK / 4;        // 1024 float4 of x per WG
constexpr int KX      = X4 / THREADS;         // 4 DMA / store iterations
constexpr int KC      = X4 / THREADS;         // 4 cp iterations per channel

// LDS holds the workgroup's 32 blocks of x (16 KB), float4-slot swizzled:
// xs4[B*32 + j'] holds sample-float4 (j' ^ (B&7)) of block B. Recurrence read
// (lane t = block) xs4[t*32 + (j ^ (t&7))] spreads 32 lanes over all 32 banks
// (4-way min for b128) instead of a 64-way row-major conflict; the
// global_load_lds destination stays linear (lane-contiguous), the swizzle is
// applied on the per-lane GLOBAL source address (m173 pattern).

__global__ __launch_bounds__(THREADS) void lowpass_kernel(
    const float* __restrict__ x,
    const float* __restrict__ cp,
    float* __restrict__ out,
    float* __restrict__ fc_out,
    float* __restrict__ q_out)
{
    __shared__ float xs[WPB * BLK];        // 16 KB
    __shared__ float ms0[WPB], ms1[WPB];   // per-block control sums

    const int t    = threadIdx.x;
    const int wg   = blockIdx.x;            // 0..2047
    const int b    = wg >> 6;               // batch row (64 wg per row)
    const int blk0 = (wg & 63) * WPB;       // first audio block of this wg

    const size_t xbase = (size_t)b * S + (size_t)blk0 * BLK;   // float index
    const float4* x4 = reinterpret_cast<const float4*>(x + xbase);

    // ---- phase 0: DMA x -> LDS, source-swizzled, dest linear --------------
#pragma unroll
    for (int k = 0; k < KX; ++k) {
        const int D  = k * THREADS + t;      // linear float4 slot in LDS
        const int B  = D >> 5;               // block row
        const int jp = D & 31;               // slot within row
        const int src4 = B * 32 + (jp ^ (B & 7));
        // wave-uniform LDS base; HW adds lane*16
        float* ldsb = xs + (size_t)(k * THREADS + (t & ~63)) * 4;
        __builtin_amdgcn_global_load_lds(
            (const __attribute__((address_space(1))) void*)(x4 + src4),
            (__attribute__((address_space(3))) void*)ldsb,
            16, 0, 0);
    }

    // ---- phase 1: control-param means (coalesced + shfl reduce) -----------
    const size_t cpb = (size_t)b * 2 * S + (size_t)blk0 * BLK;
    const float4* c0 = reinterpret_cast<const float4*>(cp + cpb);
    const float4* c1 = reinterpret_cast<const float4*>(cp + cpb + S);

    float4 v0[KC], v1[KC];
#pragma unroll
    for (int k = 0; k < KC; ++k) {
        const int f = k * THREADS + t;
        v0[k] = c0[f];
        v1[k] = c1[f];
    }
#pragma unroll
    for (int k = 0; k < KC; ++k) {
        float s0 = (v0[k].x + v0[k].y) + (v0[k].z + v0[k].w);
        float s1 = (v1[k].x + v1[k].y) + (v1[k].z + v1[k].w);
#pragma unroll
        for (int m = 1; m < 32; m <<= 1) {
            s0 += __shfl_xor(s0, m);
            s1 += __shfl_xor(s1, m);
        }
        if ((t & 31) == 0) {                 // one writer per 32-lane segment
            const int B = k * 8 + (t >> 5);  // block covered by this segment
            ms0[B] = s0;
            ms1[B] = s1;
        }
    }

    __syncthreads();   // drains the x DMA (vmcnt 0) + means visible

    // ---- phase 2+3: coeffs + 128-sample DF2T recurrence (lanes 0..31) -----
    if (t < WPB) {
        const float m0 = ms0[t] * (1.0f / BLK);
        const float m1 = ms1[t] * (1.0f / BLK);
        const float fc = m0 * (FC_MAX - FC_MIN) + FC_MIN;
        const float q  = m1 * (Q_MAX - Q_MIN) + Q_MIN;

        const int gblk = b * NB + blk0 + t;
        fc_out[gblk] = fc;
        q_out[gblk]  = q;

        const float w0 = 6.283185307179586f * fc / SRATE;
        float sw, cw;
        sincosf(w0, &sw, &cw);
        const float alpha = sw / (2.0f * q);
        const float a0inv = 1.0f / (1.0f + alpha);
        const float b0c = (1.0f - cw) * 0.5f * a0inv;   // b2 == b0
        const float b1c = (1.0f - cw) * a0inv;
        const float a1c = (-2.0f * cw) * a0inv;
        const float a2c = (1.0f - alpha) * a0inv;

        float4* xs4 = reinterpret_cast<float4*>(xs);
        const int swz = t & 7;
        float z1 = 0.0f, z2 = 0.0f;
#pragma unroll 8
        for (int j = 0; j < 32; ++j) {
            const int a = t * 32 + (j ^ swz);
            float4 xv = xs4[a];
            float4 yv;
            {   float xn = xv.x;
                float y   = b0c * xn + z1;
                float z1n = b1c * xn - a1c * y + z2;
                z2 = b0c * xn - a2c * y;  z1 = z1n;  yv.x = y; }
            {   float xn = xv.y;
                float y   = b0c * xn + z1;
                float z1n = b1c * xn - a1c * y + z2;
                z2 = b0c * xn - a2c * y;  z1 = z1n;  yv.y = y; }
            {   float xn = xv.z;
                float y   = b0c * xn + z1;
                float z1n = b1c * xn - a1c * y + z2;
                z2 = b0c * xn - a2c * y;  z1 = z1n;  yv.z = y; }
            {   float xn = xv.w;
                float y   = b0c * xn + z1;
                float z1n = b1c * xn - a1c * y + z2;
                z2 = b0c * xn - a2c * y;  z1 = z1n;  yv.w = y; }
            xs4[a] = yv;   // in-place: each lane owns its row
        }
    }

    __syncthreads();

    // ---- phase 4: cooperative coalesced store (inverse swizzle on global) -
    float4* o4 = reinterpret_cast<float4*>(out + xbase);
    const float4* xs4 = reinterpret_cast<const float4*>(xs);
#pragma unroll
    for (int k = 0; k < KX; ++k) {
        const int D  = k * THREADS + t;
        const int B  = D >> 5;
        const int jp = D & 31;
        o4[B * 32 + (jp ^ (B & 7))] = xs4[D];
    }
}

extern "C" void kernel_launch(void* const* d_in, const int* in_sizes, int n_in,
                              void* d_out, int out_size, void* d_ws, size_t ws_size,
                              hipStream_t stream) {
    const float* x  = (const float*)d_in[0];   // (32, 1, 262144)
    const float* cp = (const float*)d_in[1];   // (32, 2, 262144)

    float* out    = (float*)d_out;                      // 32*262144
    float* fc_out = out + (size_t)BATCH * S;            // 32*2048
    float* q_out  = fc_out + (size_t)BATCH * NB;        // 32*2048

    const int total_blocks = BATCH * NB;                // 65536 audio blocks
    const int grid = total_blocks / WPB;                // 2048 workgroups
    lowpass_kernel<<<grid, THREADS, 0, stream>>>(x, cp, out, fc_out, q_out);
}